// Round 1
// baseline (437.936 us; speedup 1.0000x reference)
//
#include <hip/hip_runtime.h>

#define THICKNESS 0.00047f

// One thread per face:
//  - gather 3 vertices, compute StVK energy per face
//  - scatter energy/3 into per_vert (3 atomics)
//  - block-reduce energy -> 1 atomicAdd into loss
__global__ __launch_bounds__(256) void face_energy_kernel(
    const float* __restrict__ pred_pos,   // [V,3]
    const int*   __restrict__ faces,      // [F,3] (int32 per harness)
    const float* __restrict__ Dm_inv,     // [F,2,2]
    const float* __restrict__ f_area,     // [F,1]
    const float* __restrict__ lame_mu,    // [1]
    const float* __restrict__ lame_lambda,// [1]
    float* __restrict__ out,              // [0]=loss, [1..V]=per_vert
    int F)
{
    const int f = blockIdx.x * blockDim.x + threadIdx.x;

    float energy = 0.0f;
    int i0 = 0, i1 = 0, i2 = 0;

    if (f < F) {
        i0 = faces[3 * f + 0];
        i1 = faces[3 * f + 1];
        i2 = faces[3 * f + 2];

        // gather vertices
        const float v0x = pred_pos[3 * i0 + 0];
        const float v0y = pred_pos[3 * i0 + 1];
        const float v0z = pred_pos[3 * i0 + 2];
        const float v1x = pred_pos[3 * i1 + 0];
        const float v1y = pred_pos[3 * i1 + 1];
        const float v1z = pred_pos[3 * i1 + 2];
        const float v2x = pred_pos[3 * i2 + 0];
        const float v2y = pred_pos[3 * i2 + 1];
        const float v2z = pred_pos[3 * i2 + 2];

        // Ds columns: d0 = v0 - v2, d1 = v1 - v2
        const float d0x = v0x - v2x, d0y = v0y - v2y, d0z = v0z - v2z;
        const float d1x = v1x - v2x, d1y = v1y - v2y, d1z = v1z - v2z;

        // Dm_inv row-major [2,2]: m00 m01 m10 m11  (vector load)
        const float4 m = *reinterpret_cast<const float4*>(Dm_inv + 4 * f);
        const float m00 = m.x, m01 = m.y, m10 = m.z, m11 = m.w;

        // Fg = Ds @ Dm_inv, columns F0, F1 (3-vectors)
        const float F0x = d0x * m00 + d1x * m10;
        const float F0y = d0y * m00 + d1y * m10;
        const float F0z = d0z * m00 + d1z * m10;
        const float F1x = d0x * m01 + d1x * m11;
        const float F1y = d0y * m01 + d1y * m11;
        const float F1z = d0z * m01 + d1z * m11;

        // G = 0.5 (F^T F - I)
        const float a = F0x * F0x + F0y * F0y + F0z * F0z;
        const float b = F0x * F1x + F0y * F1y + F0z * F1z;
        const float c = F1x * F1x + F1y * F1y + F1z * F1z;
        const float G00 = 0.5f * (a - 1.0f);
        const float G01 = 0.5f * b;
        const float G11 = 0.5f * (c - 1.0f);
        const float tr  = G00 + G11;

        const float mu  = lame_mu[0];
        const float lam = lame_lambda[0];

        // density = trace(S^T G) = mu*(G00^2 + 2 G01^2 + G11^2) + 0.5*lam*tr^2
        const float density = mu * (G00 * G00 + 2.0f * G01 * G01 + G11 * G11)
                            + 0.5f * lam * tr * tr;

        energy = f_area[f] * THICKNESS * density;
    }

    // ---- scatter energy/3 into per_vert ----
    if (f < F) {
        const float e3 = energy * (1.0f / 3.0f);
        atomicAdd(&out[1 + i0], e3);
        atomicAdd(&out[1 + i1], e3);
        atomicAdd(&out[1 + i2], e3);
    }

    // ---- block reduction of energy for the loss ----
    float v = energy;
    #pragma unroll
    for (int off = 32; off > 0; off >>= 1)
        v += __shfl_down(v, off, 64);

    __shared__ float wsum[4];  // 256 threads = 4 waves
    const int lane = threadIdx.x & 63;
    const int wave = threadIdx.x >> 6;
    if (lane == 0) wsum[wave] = v;
    __syncthreads();
    if (threadIdx.x == 0) {
        float s = wsum[0] + wsum[1] + wsum[2] + wsum[3];
        atomicAdd(&out[0], s);
    }
}

extern "C" void kernel_launch(void* const* d_in, const int* in_sizes, int n_in,
                              void* d_out, int out_size, void* d_ws, size_t ws_size,
                              hipStream_t stream) {
    const float* pred_pos    = (const float*)d_in[0];
    const int*   faces       = (const int*)  d_in[1];
    const float* Dm_inv      = (const float*)d_in[2];
    const float* f_area      = (const float*)d_in[3];
    const float* lame_mu     = (const float*)d_in[4];
    const float* lame_lambda = (const float*)d_in[5];
    float* out = (float*)d_out;

    const int F = in_sizes[1] / 3;   // faces flat count / 3

    // d_out is poisoned with 0xAA before every launch — zero it (loss + per_vert
    // are accumulated via atomics).
    hipMemsetAsync(d_out, 0, (size_t)out_size * sizeof(float), stream);

    const int block = 256;
    const int grid  = (F + block - 1) / block;
    face_energy_kernel<<<grid, block, 0, stream>>>(
        pred_pos, faces, Dm_inv, f_area, lame_mu, lame_lambda, out, F);
}